// Round 1
// baseline (143.385 us; speedup 1.0000x reference)
//
#include <hip/hip_runtime.h>
#include <hip/hip_bf16.h>

#define S_LEN 2048
#define DHEAD 128

typedef __bf16 bf16x8 __attribute__((ext_vector_type(8)));
typedef float  f32x4  __attribute__((ext_vector_type(4)));

__device__ __forceinline__ bf16x8 cvt8(float4 a, float4 b) {
  bf16x8 r;
  r[0] = (__bf16)a.x; r[1] = (__bf16)a.y; r[2] = (__bf16)a.z; r[3] = (__bf16)a.w;
  r[4] = (__bf16)b.x; r[5] = (__bf16)b.y; r[6] = (__bf16)b.z; r[7] = (__bf16)b.w;
  return r;
}

// Flash attention fwd, causal. Block = 256 threads = 4 waves, 64 Q rows/block.
// KV tile = 32 keys. bf16 MFMA 16x16x32, fp32 accum, fp32 output.
__global__ __launch_bounds__(256) void attn_fwd(
    const float* __restrict__ Q, const float* __restrict__ K,
    const float* __restrict__ V, float* __restrict__ Out) {
  // LDS: K tile 32x128 bf16 (8KB, XOR-swizzled) | V^T tile 128x32 bf16 (8KB) | P 4x1KB
  __shared__ __align__(16) char lds[8192 + 8192 + 4096];
  char* Klds = lds;
  char* Vlds = lds + 8192;
  char* Plds = lds + 16384 + ((threadIdx.x >> 6) << 10);

  const int tid  = threadIdx.x;
  const int wave = tid >> 6;
  const int lane = tid & 63;
  const int g    = lane >> 4;   // 16-lane group 0..3
  const int lc   = lane & 15;

  const int batch = blockIdx.x >> 5;
  const int qt    = blockIdx.x & 31;
  const int q0    = qt << 6;

  const float* Qb = Q + (size_t)batch * S_LEN * DHEAD;
  const float* Kb = K + (size_t)batch * S_LEN * DHEAD;
  const float* Vb = V + (size_t)batch * S_LEN * DHEAD;

  // ---- Q fragments in registers, pre-scaled by 1/sqrt(D) ----
  // A-layout: row = lane&15, k = 8*(lane>>4)+j (contiguous 8)
  const float scale = 0.08838834764831845f;
  const int qrow = q0 + wave * 16 + lc;
  bf16x8 qfrag[4];
#pragma unroll
  for (int db = 0; db < 4; ++db) {
    const float* src = Qb + (size_t)qrow * DHEAD + db * 32 + g * 8;
    float4 f0 = *(const float4*)(src);
    float4 f1 = *(const float4*)(src + 4);
    f0.x *= scale; f0.y *= scale; f0.z *= scale; f0.w *= scale;
    f1.x *= scale; f1.y *= scale; f1.z *= scale; f1.w *= scale;
    qfrag[db] = cvt8(f0, f1);
  }

  float m[4]    = {-INFINITY, -INFINITY, -INFINITY, -INFINITY};
  float lsum[4] = {0.f, 0.f, 0.f, 0.f};
  f32x4 o[8];
#pragma unroll
  for (int i = 0; i < 8; ++i) o[i] = (f32x4){0.f, 0.f, 0.f, 0.f};

  const int nsteps = (q0 + 64) >> 5;  // causal: only kv tiles with kv0 <= q0+63
  for (int s = 0; s < nsteps; ++s) {
    const int kv0 = s << 5;
    __syncthreads();  // protect LDS from previous iteration's readers

    // ---- stage K tile (32 kv x 128 d) bf16 row-major, swizzle ^((kv&7)<<4) ----
    {
      const int kvr = tid >> 3;          // 0..31
      const int dc  = (tid & 7) << 4;    // 0,16,...,112
      const float* src = Kb + (size_t)(kv0 + kvr) * DHEAD + dc;
      float4 a0 = *(const float4*)(src);
      float4 a1 = *(const float4*)(src + 4);
      float4 a2 = *(const float4*)(src + 8);
      float4 a3 = *(const float4*)(src + 12);
      const int base = kvr * 256 + dc * 2;
      const int swz  = (kvr & 7) << 4;
      *(bf16x8*)(Klds + ((base     ) ^ swz)) = cvt8(a0, a1);
      *(bf16x8*)(Klds + ((base + 16) ^ swz)) = cvt8(a2, a3);
    }
    // ---- stage V^T tile (128 d x 32 kv) bf16, packed kv-pairs, swizzle ^((d&3)<<4) ----
    {
      const int kv2 = tid >> 4;          // 0..15 -> kv rows 2*kv2, 2*kv2+1
      const int dc  = (tid & 15) << 3;   // 0..120
      const float* s0 = Vb + (size_t)(kv0 + 2 * kv2) * DHEAD + dc;
      const float* s1 = s0 + DHEAD;
      float4 a0 = *(const float4*)(s0);
      float4 a1 = *(const float4*)(s0 + 4);
      float4 b0 = *(const float4*)(s1);
      float4 b1 = *(const float4*)(s1 + 4);
      float fa[8] = {a0.x, a0.y, a0.z, a0.w, a1.x, a1.y, a1.z, a1.w};
      float fb[8] = {b0.x, b0.y, b0.z, b0.w, b1.x, b1.y, b1.z, b1.w};
#pragma unroll
      for (int i = 0; i < 8; ++i) {
        const int d = dc + i;
        union { __bf16 h[2]; unsigned u; } p;
        p.h[0] = (__bf16)fa[i];
        p.h[1] = (__bf16)fb[i];
        *(unsigned*)(Vlds + ((d * 64 + kv2 * 4) ^ ((d & 3) << 4))) = p.u;
      }
    }
    __syncthreads();

    // skip compute if this wave's entire 16-row q-tile is masked (uniform branch)
    if (kv0 <= q0 + wave * 16 + 15) {
      // ---- QK^T: S = Q(16x128) * K^T(128x32) ----
      f32x4 acc0 = {0.f, 0.f, 0.f, 0.f}, acc1 = {0.f, 0.f, 0.f, 0.f};
#pragma unroll
      for (int db = 0; db < 4; ++db) {
        const int koff = db * 64 + g * 16;
        bf16x8 k0 = *(const bf16x8*)(Klds + ((lc * 256 + koff) ^ ((lc & 7) << 4)));
        bf16x8 k1 = *(const bf16x8*)(Klds + (((lc + 16) * 256 + koff) ^ (((lc + 16) & 7) << 4)));
        acc0 = __builtin_amdgcn_mfma_f32_16x16x32_bf16(qfrag[db], k0, acc0, 0, 0, 0);
        acc1 = __builtin_amdgcn_mfma_f32_16x16x32_bf16(qfrag[db], k1, acc1, 0, 0, 0);
      }

      // ---- online softmax. C-layout: col kv = lc, row q = 4*g + r ----
      const int rbase = q0 + wave * 16 + 4 * g;
      float tmax[4];
#pragma unroll
      for (int r = 0; r < 4; ++r) {
        const int qr = rbase + r;
        const float t0 = (kv0 + lc      <= qr) ? acc0[r] : -INFINITY;
        const float t1 = (kv0 + 16 + lc <= qr) ? acc1[r] : -INFINITY;
        tmax[r] = fmaxf(t0, t1);
      }
#pragma unroll
      for (int msk = 1; msk <= 8; msk <<= 1) {
#pragma unroll
        for (int r = 0; r < 4; ++r)
          tmax[r] = fmaxf(tmax[r], __shfl_xor(tmax[r], msk, 64));
      }

      float alpha[4], rsum[4];
#pragma unroll
      for (int r = 0; r < 4; ++r) {
        const int qr = rbase + r;
        const float mn = fmaxf(m[r], tmax[r]);
        alpha[r] = (m[r] == -INFINITY) ? 0.f : __expf(m[r] - mn);
        const bool v0 = (kv0 + lc      <= qr);
        const bool v1 = (kv0 + 16 + lc <= qr);
        const float p0 = v0 ? __expf(acc0[r] - mn) : 0.f;
        const float p1 = v1 ? __expf(acc1[r] - mn) : 0.f;
        rsum[r] = p0 + p1;
        // write P (bf16) to per-wave LDS, row = 4g+r, cols lc and lc+16
        const int row = 4 * g + r;
        const int swz = (row & 3) << 4;
        *(__bf16*)(Plds + ((row * 64 + lc * 2)        ^ swz)) = (__bf16)p0;
        *(__bf16*)(Plds + ((row * 64 + (lc + 16) * 2) ^ swz)) = (__bf16)p1;
        m[r] = mn;
      }
#pragma unroll
      for (int msk = 1; msk <= 8; msk <<= 1) {
#pragma unroll
        for (int r = 0; r < 4; ++r)
          rsum[r] += __shfl_xor(rsum[r], msk, 64);
      }
#pragma unroll
      for (int r = 0; r < 4; ++r) lsum[r] = lsum[r] * alpha[r] + rsum[r];
#pragma unroll
      for (int i = 0; i < 8; ++i) {
#pragma unroll
        for (int r = 0; r < 4; ++r) o[i][r] *= alpha[r];
      }

      // ---- PV: O += P(16x32) * V(32x128) ----
      // A-frag of P: row = lc, k = 8g+j (one frag reused for all 8 d-blocks)
      bf16x8 pf = *(const bf16x8*)(Plds + ((lc * 64 + g * 16) ^ ((lc & 3) << 4)));
#pragma unroll
      for (int dblk = 0; dblk < 8; ++dblk) {
        const int d = dblk * 16 + lc;
        bf16x8 vf = *(const bf16x8*)(Vlds + ((d * 64 + g * 16) ^ ((d & 3) << 4)));
        o[dblk] = __builtin_amdgcn_mfma_f32_16x16x32_bf16(pf, vf, o[dblk], 0, 0, 0);
      }
    }
  }

  // ---- epilogue: normalize and store fp32 ----
#pragma unroll
  for (int r = 0; r < 4; ++r) {
    const int qr = q0 + wave * 16 + 4 * g + r;
    const float inv = 1.f / lsum[r];
    float* dst = Out + ((size_t)(batch * S_LEN + qr)) * DHEAD;
#pragma unroll
    for (int dblk = 0; dblk < 8; ++dblk)
      dst[dblk * 16 + lc] = o[dblk][r] * inv;
  }
}

extern "C" void kernel_launch(void* const* d_in, const int* in_sizes, int n_in,
                              void* d_out, int out_size, void* d_ws, size_t ws_size,
                              hipStream_t stream) {
  const float* q = (const float*)d_in[0];
  const float* k = (const float*)d_in[1];
  const float* v = (const float*)d_in[2];
  float* out = (float*)d_out;
  const int B = in_sizes[0] / (S_LEN * DHEAD);
  dim3 grid(B * (S_LEN / 64));
  attn_fwd<<<grid, dim3(256), 0, stream>>>(q, k, v, out);
}

// Round 2
// 98.721 us; speedup vs baseline: 1.4524x; 1.4524x over previous
//
#include <hip/hip_runtime.h>
#include <hip/hip_bf16.h>

#define S_LEN 2048
#define DHEAD 128
#define VSTR  160   // V^T LDS row stride in bytes (128B data + 32B pad -> bank-phase spread)

typedef __bf16 bf16x8 __attribute__((ext_vector_type(8)));
typedef float  f32x4  __attribute__((ext_vector_type(4)));

__device__ __forceinline__ bf16x8 cvt8(float4 a, float4 b) {
  bf16x8 r;
  r[0] = (__bf16)a.x; r[1] = (__bf16)a.y; r[2] = (__bf16)a.z; r[3] = (__bf16)a.w;
  r[4] = (__bf16)b.x; r[5] = (__bf16)b.y; r[6] = (__bf16)b.z; r[7] = (__bf16)b.w;
  return r;
}

// Flash attention fwd, causal. Block = 256 thr = 4 waves, 32 Q rows/block.
// Waves {0,1}: rows [0,16),[16,32) x even 32-key halves; waves {2,3}: same rows, odd halves.
// 64-key KV tiles, register prefetch (T14), partial-softmax merge at end.
__global__ __launch_bounds__(256, 2) void attn_fwd(
    const float* __restrict__ Q, const float* __restrict__ K,
    const float* __restrict__ V, float* __restrict__ Out) {
  // LDS: K tile 64x256B (16KB) | V^T tile 128xVSTR (20KB) | P 4x1KB
  __shared__ __align__(16) char lds[16384 + 128 * VSTR + 4096];
  char* Klds = lds;
  char* Vlds = lds + 16384;
  char* Plds = lds + 16384 + 128 * VSTR + ((threadIdx.x >> 6) << 10);

  const int tid  = threadIdx.x;
  const int w    = tid >> 6;
  const int lane = tid & 63;
  const int g    = lane >> 4;
  const int lc   = lane & 15;
  const int p    = w >> 1;   // kv parity (0: keys [0,32) of tile, 1: keys [32,64))
  const int rh   = w & 1;    // row half within the 32-row q-tile

  const int bi    = blockIdx.x;
  const int batch = bi & 7;              // consecutive blocks -> different batches (XCD L2 locality)
  const int t     = 63 - (bi >> 3);      // long (high-t) q-tiles dispatched first
  const int q0    = t << 5;

  const float* Qb = Q + (size_t)batch * S_LEN * DHEAD;
  const float* Kb = K + (size_t)batch * S_LEN * DHEAD;
  const float* Vb = V + (size_t)batch * S_LEN * DHEAD;

  // ---- Q fragments in registers, pre-scaled ----
  const float scale = 0.08838834764831845f;
  const int qrow = q0 + rh * 16 + lc;
  bf16x8 qfrag[4];
#pragma unroll
  for (int db = 0; db < 4; ++db) {
    const float* src = Qb + (size_t)qrow * DHEAD + db * 32 + g * 8;
    float4 f0 = *(const float4*)(src);
    float4 f1 = *(const float4*)(src + 4);
    f0.x *= scale; f0.y *= scale; f0.z *= scale; f0.w *= scale;
    f1.x *= scale; f1.y *= scale; f1.z *= scale; f1.w *= scale;
    qfrag[db] = cvt8(f0, f1);
  }

  float m[4]    = {-INFINITY, -INFINITY, -INFINITY, -INFINITY};
  float lsum[4] = {0.f, 0.f, 0.f, 0.f};
  f32x4 o[8];
#pragma unroll
  for (int i = 0; i < 8; ++i) o[i] = (f32x4){0.f, 0.f, 0.f, 0.f};

  // staging thread maps
  const int kvrK = tid >> 2;         // 0..63  K row
  const int dqK  = tid & 3;          // 32-float chunk of the row
  const int kv2V = tid & 15;         // kv pair index within 32-key half
  const int dcV  = (tid >> 4) << 3;  // 0..120, 8 d's per thread

  // prefetch registers
  float4 kf[8];
  float4 va0[2], va1[2], vb0[2], vb1[2];  // V rows 2kv2, 2kv2+1, 32+2kv2, 33+2kv2

  const int nit = (q0 + 95) >> 6;  // ceil((q0+32)/64)

  auto load_tiles = [&](int kv0) {
    const float4* ks = (const float4*)(Kb + (size_t)(kv0 + kvrK) * DHEAD + dqK * 32);
#pragma unroll
    for (int j = 0; j < 8; ++j) kf[j] = ks[j];
    const float* v0 = Vb + (size_t)(kv0 + 2 * kv2V) * DHEAD + dcV;
    va0[0] = *(const float4*)(v0);          va0[1] = *(const float4*)(v0 + 4);
    va1[0] = *(const float4*)(v0 + DHEAD);  va1[1] = *(const float4*)(v0 + DHEAD + 4);
    const float* v1 = v0 + 32 * DHEAD;
    vb0[0] = *(const float4*)(v1);          vb0[1] = *(const float4*)(v1 + 4);
    vb1[0] = *(const float4*)(v1 + DHEAD);  vb1[1] = *(const float4*)(v1 + DHEAD + 4);
  };

  load_tiles(0);

  for (int it = 0; it < nit; ++it) {
    __syncthreads();  // prev compute done reading LDS; drains vmcnt (prefetch regs ready)

    // ---- K LDS write: row kvrK, swizzle ^((kv&7)<<4) ----
    {
      const int kswz = (kvrK & 7) << 4;
      const int kbase = kvrK * 256;
#pragma unroll
      for (int j = 0; j < 4; ++j)
        *(bf16x8*)(Klds + kbase + ((dqK * 64 + j * 16) ^ kswz)) = cvt8(kf[2 * j], kf[2 * j + 1]);
    }
    // ---- V^T LDS write: pair-packed, row stride VSTR, swizzle ^((d&7)<<4) ----
    {
      float fa0[8] = {va0[0].x, va0[0].y, va0[0].z, va0[0].w, va0[1].x, va0[1].y, va0[1].z, va0[1].w};
      float fa1[8] = {va1[0].x, va1[0].y, va1[0].z, va1[0].w, va1[1].x, va1[1].y, va1[1].z, va1[1].w};
      float fb0[8] = {vb0[0].x, vb0[0].y, vb0[0].z, vb0[0].w, vb0[1].x, vb0[1].y, vb0[1].z, vb0[1].w};
      float fb1[8] = {vb1[0].x, vb1[0].y, vb1[0].z, vb1[0].w, vb1[1].x, vb1[1].y, vb1[1].z, vb1[1].w};
#pragma unroll
      for (int i = 0; i < 8; ++i) {
        const int d  = dcV + i;
        const int sw = (d & 7) << 4;
        union { __bf16 h[2]; unsigned u; } pa, pb;
        pa.h[0] = (__bf16)fa0[i]; pa.h[1] = (__bf16)fa1[i];
        pb.h[0] = (__bf16)fb0[i]; pb.h[1] = (__bf16)fb1[i];
        *(unsigned*)(Vlds + d * VSTR + ((kv2V * 4) ^ sw))        = pa.u;
        *(unsigned*)(Vlds + d * VSTR + (((kv2V + 16) * 4) ^ sw)) = pb.u;
      }
    }

    // ---- issue next-tile loads; they fly during this tile's compute ----
    if (it + 1 < nit) load_tiles((it + 1) * 64);

    asm volatile("s_waitcnt lgkmcnt(0)" ::: "memory");  // staging writes visible
    __builtin_amdgcn_s_barrier();                        // NO vmcnt drain: prefetch stays in flight
    __builtin_amdgcn_sched_barrier(0);

    const int kvb = it * 64 + p * 32;  // this wave's 32-key base
    if (kvb <= q0 + rh * 16 + 15) {    // uniform per-wave causal skip
      // ---- QK^T ----
      f32x4 acc0 = {0.f, 0.f, 0.f, 0.f}, acc1 = {0.f, 0.f, 0.f, 0.f};
      const int r0 = p * 32 + lc;
#pragma unroll
      for (int db = 0; db < 4; ++db) {
        const int koff = db * 64 + g * 16;
        bf16x8 k0 = *(const bf16x8*)(Klds + r0 * 256 + (koff ^ ((r0 & 7) << 4)));
        bf16x8 k1 = *(const bf16x8*)(Klds + (r0 + 16) * 256 + (koff ^ ((r0 & 7) << 4)));
        acc0 = __builtin_amdgcn_mfma_f32_16x16x32_bf16(qfrag[db], k0, acc0, 0, 0, 0);
        acc1 = __builtin_amdgcn_mfma_f32_16x16x32_bf16(qfrag[db], k1, acc1, 0, 0, 0);
      }

      // ---- online softmax (C layout: col kv = lc, row q = 4g+r) ----
      const int rbase = q0 + rh * 16 + 4 * g;
      float tmax[4];
#pragma unroll
      for (int r = 0; r < 4; ++r) {
        const int qr = rbase + r;
        const float t0 = (kvb + lc      <= qr) ? acc0[r] : -INFINITY;
        const float t1 = (kvb + 16 + lc <= qr) ? acc1[r] : -INFINITY;
        tmax[r] = fmaxf(t0, t1);
      }
#pragma unroll
      for (int msk = 1; msk <= 8; msk <<= 1) {
#pragma unroll
        for (int r = 0; r < 4; ++r)
          tmax[r] = fmaxf(tmax[r], __shfl_xor(tmax[r], msk, 64));
      }

      float alpha[4], rsum[4];
#pragma unroll
      for (int r = 0; r < 4; ++r) {
        const int qr = rbase + r;
        const float mn = fmaxf(m[r], tmax[r]);
        alpha[r] = (m[r] == -INFINITY) ? 0.f : __expf(m[r] - mn);
        const float p0 = (kvb + lc      <= qr) ? __expf(acc0[r] - mn) : 0.f;
        const float p1 = (kvb + 16 + lc <= qr) ? __expf(acc1[r] - mn) : 0.f;
        rsum[r] = p0 + p1;
        const int row = 4 * g + r;
        const int swp = (row & 3) << 4;
        *(__bf16*)(Plds + ((row * 64 + lc * 2)        ^ swp)) = (__bf16)p0;
        *(__bf16*)(Plds + ((row * 64 + (lc + 16) * 2) ^ swp)) = (__bf16)p1;
        m[r] = mn;
      }
#pragma unroll
      for (int msk = 1; msk <= 8; msk <<= 1) {
#pragma unroll
        for (int r = 0; r < 4; ++r)
          rsum[r] += __shfl_xor(rsum[r], msk, 64);
      }
#pragma unroll
      for (int r = 0; r < 4; ++r) lsum[r] = lsum[r] * alpha[r] + rsum[r];
#pragma unroll
      for (int i = 0; i < 8; ++i) {
#pragma unroll
        for (int r = 0; r < 4; ++r) o[i][r] *= alpha[r];
      }

      // ---- PV ----
      bf16x8 pf = *(const bf16x8*)(Plds + ((lc * 64 + g * 16) ^ ((lc & 3) << 4)));
#pragma unroll
      for (int dblk = 0; dblk < 8; ++dblk) {
        const int d = dblk * 16 + lc;
        bf16x8 vf = *(const bf16x8*)(Vlds + d * VSTR + ((p * 64 + g * 16) ^ ((d & 7) << 4)));
        o[dblk] = __builtin_amdgcn_mfma_f32_16x16x32_bf16(pf, vf, o[dblk], 0, 0, 0);
      }
    }
  }

  // ---- merge even/odd kv partials (waves w and w+2 share rows), store ----
  __syncthreads();
  float* mlds = (float*)lds;
  if (w >= 2) {
    float* dst = mlds + (size_t)(rh * 64 + lane) * 40;
#pragma unroll
    for (int r = 0; r < 4; ++r) { dst[r] = m[r]; dst[4 + r] = lsum[r]; }
#pragma unroll
    for (int dblk = 0; dblk < 8; ++dblk)
#pragma unroll
      for (int r = 0; r < 4; ++r) dst[8 + dblk * 4 + r] = o[dblk][r];
  }
  __syncthreads();
  if (w < 2) {
    const float* src = mlds + (size_t)(rh * 64 + lane) * 40;
#pragma unroll
    for (int r = 0; r < 4; ++r) {
      const float mB = src[r], lB = src[4 + r];
      const float M  = fmaxf(m[r], mB);
      const float fA = (m[r] == -INFINITY) ? 0.f : __expf(m[r] - M);
      const float fB = (mB   == -INFINITY) ? 0.f : __expf(mB   - M);
      const float L  = lsum[r] * fA + lB * fB;
      const float inv = 1.f / L;
      const int qr = q0 + rh * 16 + 4 * g + r;
      float* dst = Out + ((size_t)(batch * S_LEN + qr)) * DHEAD;
#pragma unroll
      for (int dblk = 0; dblk < 8; ++dblk)
        dst[dblk * 16 + lc] = (o[dblk][r] * fA + src[8 + dblk * 4 + r] * fB) * inv;
    }
  }
}

extern "C" void kernel_launch(void* const* d_in, const int* in_sizes, int n_in,
                              void* d_out, int out_size, void* d_ws, size_t ws_size,
                              hipStream_t stream) {
  const float* q = (const float*)d_in[0];
  const float* k = (const float*)d_in[1];
  const float* v = (const float*)d_in[2];
  float* out = (float*)d_out;
  const int B = in_sizes[0] / (S_LEN * DHEAD);
  dim3 grid(B * (S_LEN / 32));
  attn_fwd<<<grid, dim3(256), 0, stream>>>(q, k, v, out);
}

// Round 3
// 74.612 us; speedup vs baseline: 1.9217x; 1.3231x over previous
//
#include <hip/hip_runtime.h>
#include <hip/hip_bf16.h>

#define S_LEN 2048
#define DHEAD 128
#define VROW  72   // V^T LDS row stride in bytes (64B data + 8B pad -> bank spread)

typedef __bf16 bf16x8 __attribute__((ext_vector_type(8)));
typedef float  f32x16 __attribute__((ext_vector_type(16)));

union F4 { float4 v; float f[4]; };
union PK { __bf16 h[2]; unsigned u; };
union BW { unsigned w4[4]; bf16x8 v; };

struct TrueT  { static constexpr bool value = true;  };
struct FalseT { static constexpr bool value = false; };

__device__ __forceinline__ bf16x8 cvt8(float4 a, float4 b) {
  bf16x8 r;
  r[0] = (__bf16)a.x; r[1] = (__bf16)a.y; r[2] = (__bf16)a.z; r[3] = (__bf16)a.w;
  r[4] = (__bf16)b.x; r[5] = (__bf16)b.y; r[6] = (__bf16)b.z; r[7] = (__bf16)b.w;
  return r;
}

// Flash attention fwd, causal. Block = 4 waves over the SAME 32 q rows,
// 4-way kv-parity split (wave w does kv tiles t%4==w), zero per-tile barriers.
// S^T = mfma(K,Q) 32x32x16 -> in-register softmax (1 shfl_xor(32) per reduce).
// O^T = mfma(V^T, P^T). K,Q direct global->reg; V^T staged per-wave in LDS.
__global__ __launch_bounds__(256, 2) void attn_fwd(
    const float* __restrict__ Q, const float* __restrict__ K,
    const float* __restrict__ V, float* __restrict__ Out) {
  // LDS map: [0, 36864): 4 x 9216B per-wave V^T buffers (compute phase)
  //          epilogue overlay: Obuf0 @0 (32x132 f32), Obuf1 @16896
  //          [36864, 37888): float2 ml[4][32]; [37888, 38016): float Lbuf[32]
  __shared__ __align__(16) char lds[38016];

  const int tid  = threadIdx.x;
  const int w    = tid >> 6;
  const int lane = tid & 63;
  const int h    = lane >> 5;   // half-wave
  const int lq   = lane & 31;   // q row within tile (and d row for V-frags)

  const int bi    = blockIdx.x;
  const int batch = bi & 7;
  const int T     = (bi < 256) ? (63 - (bi >> 3)) : ((bi - 256) >> 3);  // long+short pairing
  const int q0    = T << 5;
  const int q     = q0 + lq;

  const float* Qb = Q + (size_t)batch * S_LEN * DHEAD;
  const float* Kb = K + (size_t)batch * S_LEN * DHEAD;
  const float* Vb = V + (size_t)batch * S_LEN * DHEAD;

  char* Vw = lds + w * 9216;

  // ---- Q fragments (B-operand: col=q=lane&31, k=8h+j), pre-scaled ----
  const float scale = 0.08838834764831845f;
  bf16x8 qf[8];
  {
    const float* qp = Qb + (size_t)q * DHEAD + 8 * h;
#pragma unroll
    for (int ks = 0; ks < 8; ++ks) {
      float4 a = *(const float4*)(qp + 16 * ks);
      float4 b = *(const float4*)(qp + 16 * ks + 4);
      a.x *= scale; a.y *= scale; a.z *= scale; a.w *= scale;
      b.x *= scale; b.y *= scale; b.z *= scale; b.w *= scale;
      qf[ks] = cvt8(a, b);
    }
  }

  float  mrun = -INFINITY, lrun = 0.f;
  f32x16 ob[4];
#pragma unroll
  for (int db = 0; db < 4; ++db)
#pragma unroll
    for (int r = 0; r < 16; ++r) ob[db][r] = 0.f;

  // staging maps
  const int kv2 = lane & 15;          // V kv-pair index (rows 2kv2, 2kv2+1)
  const int dc0 = (lane >> 4) << 3;   // V d base {0,8,16,24}; +32c covers 128

  F4 kst[16];  // K fp32 prefetch (one tile)
  F4 vh[8];    // V fp32 half-tile staging

  auto issueK = [&](int t) {
    const float* kp = Kb + (size_t)(t * 32 + lq) * DHEAD + 8 * h;
#pragma unroll
    for (int ks = 0; ks < 8; ++ks) {
      kst[2 * ks + 0].v = *(const float4*)(kp + 16 * ks);
      kst[2 * ks + 1].v = *(const float4*)(kp + 16 * ks + 4);
    }
  };
  auto issueVhalf = [&](int kv0, int cbase) {
#pragma unroll
    for (int cc = 0; cc < 2; ++cc) {
      const float* s0 = Vb + (size_t)(kv0 + 2 * kv2) * DHEAD + dc0 + 32 * (cbase + cc);
      vh[4 * cc + 0].v = *(const float4*)(s0);
      vh[4 * cc + 1].v = *(const float4*)(s0 + 4);
      vh[4 * cc + 2].v = *(const float4*)(s0 + DHEAD);
      vh[4 * cc + 3].v = *(const float4*)(s0 + DHEAD + 4);
    }
  };
  auto writeVhalf = [&](int cbase) {
#pragma unroll
    for (int cc = 0; cc < 2; ++cc) {
#pragma unroll
      for (int i = 0; i < 8; ++i) {
        const int d = dc0 + 32 * (cbase + cc) + i;
        PK pk;
        pk.h[0] = (__bf16)vh[4 * cc + (i >> 2)].f[i & 3];
        pk.h[1] = (__bf16)vh[4 * cc + 2 + (i >> 2)].f[i & 3];
        *(unsigned*)(Vw + d * VROW + kv2 * 4) = pk.u;
      }
    }
  };

  auto tile = [&](int t, auto diagc) {
    constexpr bool DIAG = decltype(diagc)::value;
    const int kv0 = t << 5;

    issueVhalf(kv0, 0);  // V half A (d 0..63) in flight during QK^T+softmax

    // K cvt (vmcnt-waits on kst from previous issueK)
    bf16x8 kf[8];
#pragma unroll
    for (int ks = 0; ks < 8; ++ks) kf[ks] = cvt8(kst[2 * ks].v, kst[2 * ks + 1].v);

    // ---- S^T = K * Q^T  (two independent 4-chains over d) ----
    f32x16 sa, sb;
#pragma unroll
    for (int r = 0; r < 16; ++r) { sa[r] = 0.f; sb[r] = 0.f; }
#pragma unroll
    for (int ks = 0; ks < 4; ++ks)
      sa = __builtin_amdgcn_mfma_f32_32x32x16_bf16(kf[ks], qf[ks], sa, 0, 0, 0);
#pragma unroll
    for (int ks = 4; ks < 8; ++ks)
      sb = __builtin_amdgcn_mfma_f32_32x32x16_bf16(kf[ks], qf[ks], sb, 0, 0, 0);
    f32x16 sv;
#pragma unroll
    for (int r = 0; r < 16; ++r) sv[r] = sa[r] + sb[r];

    // ---- in-register softmax (lane owns a 16-elem P column of row q) ----
    bool ok[16];
    if constexpr (DIAG) {
#pragma unroll
      for (int r = 0; r < 16; ++r) {
        const int kvr = kv0 + (r & 3) + 8 * (r >> 2) + 4 * h;
        ok[r] = (kvr <= q);
        sv[r] = ok[r] ? sv[r] : -INFINITY;
      }
    }
    float mx = sv[0];
#pragma unroll
    for (int r = 1; r < 16; ++r) mx = fmaxf(mx, sv[r]);
    mx = fmaxf(mx, __shfl_xor(mx, 32));

    float mnew = mrun;                       // T13 defer-max
    if (__any(mx > mrun + 8.f)) {
      mnew = fmaxf(mrun, mx);
      const float alpha = __expf(mrun - mnew);  // 0 if mrun==-inf
      lrun *= alpha;
#pragma unroll
      for (int db = 0; db < 4; ++db)
#pragma unroll
        for (int r = 0; r < 16; ++r) ob[db][r] *= alpha;
      mrun = mnew;
    }

    float pv[16];
    float rsum = 0.f;
#pragma unroll
    for (int r = 0; r < 16; ++r) {
      float e = __expf(sv[r] - mnew);
      if constexpr (DIAG) e = ok[r] ? e : 0.f;  // kills exp(-inf - -inf) NaN
      pv[r] = e;
      rsum += e;
    }
    rsum += __shfl_xor(rsum, 32);
    lrun += rsum;

    // ---- P -> bf16 packs + half-wave exchange (T12) ----
    unsigned c[8];
#pragma unroll
    for (int i = 0; i < 8; ++i) {
      PK pk;
      pk.h[0] = (__bf16)pv[2 * i];
      pk.h[1] = (__bf16)pv[2 * i + 1];
      c[i] = pk.u;
    }
    const unsigned e0 = (unsigned)__shfl_xor((int)(h ? c[0] : c[2]), 32);
    const unsigned e1 = (unsigned)__shfl_xor((int)(h ? c[1] : c[3]), 32);
    const unsigned e2 = (unsigned)__shfl_xor((int)(h ? c[4] : c[6]), 32);
    const unsigned e3 = (unsigned)__shfl_xor((int)(h ? c[5] : c[7]), 32);
    BW pb0, pb1;
    pb0.w4[0] = h ? e0   : c[0];
    pb0.w4[1] = h ? e1   : c[1];
    pb0.w4[2] = h ? c[2] : e0;
    pb0.w4[3] = h ? c[3] : e1;
    pb1.w4[0] = h ? e2   : c[4];
    pb1.w4[1] = h ? e3   : c[5];
    pb1.w4[2] = h ? c[6] : e2;
    pb1.w4[3] = h ? c[7] : e3;

    // ---- V half A -> LDS; issue half B ----
    writeVhalf(0);
    issueVhalf(kv0, 2);

    // ---- PV for d 0..63 (O^T = V^T * P^T) ----
#pragma unroll
    for (int db = 0; db < 2; ++db) {
      const char* vp = Vw + (32 * db + lq) * VROW;
      bf16x8 a0 = *(const bf16x8*)(vp + (8 * h) * 2);
      ob[db] = __builtin_amdgcn_mfma_f32_32x32x16_bf16(a0, pb0.v, ob[db], 0, 0, 0);
      bf16x8 a1 = *(const bf16x8*)(vp + (16 + 8 * h) * 2);
      ob[db] = __builtin_amdgcn_mfma_f32_32x32x16_bf16(a1, pb1.v, ob[db], 0, 0, 0);
    }

    // ---- V half B -> LDS; prefetch next K; PV for d 64..127 ----
    writeVhalf(2);
    if (t + 4 <= T) issueK(t + 4);
#pragma unroll
    for (int db = 2; db < 4; ++db) {
      const char* vp = Vw + (32 * db + lq) * VROW;
      bf16x8 a0 = *(const bf16x8*)(vp + (8 * h) * 2);
      ob[db] = __builtin_amdgcn_mfma_f32_32x32x16_bf16(a0, pb0.v, ob[db], 0, 0, 0);
      bf16x8 a1 = *(const bf16x8*)(vp + (16 + 8 * h) * 2);
      ob[db] = __builtin_amdgcn_mfma_f32_32x32x16_bf16(a1, pb1.v, ob[db], 0, 0, 0);
    }
  };

  if (w <= T) {
    issueK(w);
    for (int t = w; t <= T; t += 4) {
      if (t == T) tile(t, TrueT{});
      else        tile(t, FalseT{});
    }
  }

  // ================= merge 4 kv-parity partials =================
  float2* ml   = (float2*)(lds + 36864);
  float*  Lbuf = (float*)(lds + 37888);
  float*  Ob0  = (float*)(lds);
  float*  Ob1  = (float*)(lds + 16896);

  if (h == 0) ml[w * 32 + lq] = make_float2(mrun, lrun);
  __syncthreads();

  float M = -INFINITY;
#pragma unroll
  for (int ww = 0; ww < 4; ++ww) M = fmaxf(M, ml[ww * 32 + lq].x);
  float L = 0.f;
#pragma unroll
  for (int ww = 0; ww < 4; ++ww) {
    float2 v = ml[ww * 32 + lq];
    L += v.y * __expf(v.x - M);   // 0-contribution for idle waves (m=-inf)
  }
  const float fw = __expf(mrun - M);
  if (w == 0 && h == 0) Lbuf[lq] = 1.f / L;

  float* Ob = (w & 1) ? Ob1 : Ob0;
  if (w < 2) {
#pragma unroll
    for (int db = 0; db < 4; ++db)
#pragma unroll
      for (int rr = 0; rr < 4; ++rr) {
        float4 val = { ob[db][4 * rr + 0] * fw, ob[db][4 * rr + 1] * fw,
                       ob[db][4 * rr + 2] * fw, ob[db][4 * rr + 3] * fw };
        *(float4*)(Ob + lq * 132 + 32 * db + 8 * rr + 4 * h) = val;
      }
  }
  __syncthreads();
  if (w >= 2) {
#pragma unroll
    for (int db = 0; db < 4; ++db)
#pragma unroll
      for (int rr = 0; rr < 4; ++rr) {
        float* p = Ob + lq * 132 + 32 * db + 8 * rr + 4 * h;
        float4 cur = *(float4*)p;
        cur.x += ob[db][4 * rr + 0] * fw;
        cur.y += ob[db][4 * rr + 1] * fw;
        cur.z += ob[db][4 * rr + 2] * fw;
        cur.w += ob[db][4 * rr + 3] * fw;
        *(float4*)p = cur;
      }
  }
  __syncthreads();

  // ---- cooperative coalesced store ----
  const int row = tid >> 3;
  const int d0  = (tid & 7) * 16;
  const float inv = Lbuf[row];
  float* orow = Out + ((size_t)(batch * S_LEN + q0 + row)) * DHEAD + d0;
#pragma unroll
  for (int j = 0; j < 4; ++j) {
    float4 a = *(float4*)(Ob0 + row * 132 + d0 + 4 * j);
    float4 b = *(float4*)(Ob1 + row * 132 + d0 + 4 * j);
    float4 o = { (a.x + b.x) * inv, (a.y + b.y) * inv,
                 (a.z + b.z) * inv, (a.w + b.w) * inv };
    *(float4*)(orow + 4 * j) = o;
  }
}

extern "C" void kernel_launch(void* const* d_in, const int* in_sizes, int n_in,
                              void* d_out, int out_size, void* d_ws, size_t ws_size,
                              hipStream_t stream) {
  const float* q = (const float*)d_in[0];
  const float* k = (const float*)d_in[1];
  const float* v = (const float*)d_in[2];
  float* out = (float*)d_out;
  const int B = in_sizes[0] / (S_LEN * DHEAD);
  dim3 grid(B * (S_LEN / 32));
  attn_fwd<<<grid, dim3(256), 0, stream>>>(q, k, v, out);
}